// Round 5
// baseline (121.015 us; speedup 1.0000x reference)
//
#include <hip/hip_runtime.h>
#include <hip/hip_bf16.h>

#define NNODES 131072
#define NEDGES 2097152
#define BSUB   1024
#define SSUB   128
#define FIN    300
#define FOUT   64
#define NCHUNK 256
#define CHEDGE 8192

typedef __attribute__((ext_vector_type(8))) short short8;
typedef __attribute__((ext_vector_type(8))) unsigned short ushort8;
typedef __attribute__((ext_vector_type(4))) float f32x4;

// hardware RNE f32->bf16 (compiler lowers pairs to v_cvt_pk_bf16_f32)
__device__ inline unsigned short f2bfbits(float f) {
    union { __hip_bfloat16 h; unsigned short u; } cv;
    cv.h = __float2bfloat16(f);
    return cv.u;
}
__device__ inline float bf2f(unsigned short b) {
    return __uint_as_float(((unsigned)b) << 16);
}

// ---------------------------------------------------------------------------
// Pack W [300][64] f32 into MFMA B-fragment layout (K padded to 320) AND
// zero the 1024-entry gcnt array (a graph memset node costs ~91 us/replay).
// ---------------------------------------------------------------------------
__global__ __launch_bounds__(256) void prep_w_kernel(const float* __restrict__ W,
                                                     short* __restrict__ wfrag,
                                                     int* __restrict__ gcnt) {
    int idx = blockIdx.x * 256 + threadIdx.x;     // grid 10 x 256 = 2560
    if (idx < BSUB) gcnt[idx] = 0;
    if (idx >= 2560) return;
    int ct   = idx / 640;
    int rem  = idx % 640;
    int kt   = rem / 64;
    int lane = rem % 64;
    int col  = ct * 16 + (lane & 15);
    int kb   = kt * 32 + (lane >> 4) * 8;
#pragma unroll
    for (int e = 0; e < 8; ++e) {
        int k = kb + e;
        float v = (k < FIN) ? W[(size_t)k * FOUT + col] : 0.f;
        wfrag[(size_t)idx * 8 + e] = (short)f2bfbits(v);
    }
}

// ---------------------------------------------------------------------------
// Single-pass edge bucketing: stage chunk edges in LDS, histogram, reserve a
// range per (chunk, subgraph) with ONE global atomic per nonzero bin, scatter
// packed (src_loc<<7 | dst_loc) u16 edges into fixed 4096-entry buckets.
// ---------------------------------------------------------------------------
__global__ __launch_bounds__(256) void bucket_kernel(const int* __restrict__ src,
                                                     const int* __restrict__ dst,
                                                     int* __restrict__ gcnt,
                                                     unsigned short* __restrict__ bkt) {
    __shared__ unsigned short epack[CHEDGE];   // 16 KB
    __shared__ unsigned short eg[CHEDGE];      // 16 KB
    __shared__ int hist[BSUB];                 // 4 KB (hist, then cursor)
    const int t = threadIdx.x;
    for (int i = t; i < BSUB; i += 256) hist[i] = 0;
    __syncthreads();
    const int4* sp = (const int4*)(src + (size_t)blockIdx.x * CHEDGE);
    const int4* dp = (const int4*)(dst + (size_t)blockIdx.x * CHEDGE);
    for (int i = t; i < CHEDGE / 4; i += 256) {
        int4 s4 = sp[i], d4 = dp[i];
#pragma unroll
        for (int k = 0; k < 4; ++k) {
            int s = (k == 0) ? s4.x : (k == 1) ? s4.y : (k == 2) ? s4.z : s4.w;
            int d = (k == 0) ? d4.x : (k == 1) ? d4.y : (k == 2) ? d4.z : d4.w;
            int g = s >> 7;
            epack[i * 4 + k] = (unsigned short)(((s & 127) << 7) | (d & 127));
            eg[i * 4 + k] = (unsigned short)g;
            atomicAdd(&hist[g], 1);
        }
    }
    __syncthreads();
    for (int i = t; i < BSUB; i += 256) {
        int c = hist[i];
        hist[i] = c ? atomicAdd(&gcnt[i], c) : 0;   // hist becomes running cursor
    }
    __syncthreads();
    for (int i = t; i < CHEDGE; i += 256) {
        int g = eg[i];
        int r = atomicAdd(&hist[g], 1);
        bkt[((size_t)g << 12) + r] = epack[i];
    }
}

// ---------------------------------------------------------------------------
// h = in_feat @ W (unnormalized), bf16 MFMA 16x16x32, bf16 output.
// One wave per 16 rows; A-frags loaded straight from global f32, hw-cvt bf16.
// ---------------------------------------------------------------------------
__global__ __launch_bounds__(256) void gemm_kernel(const float* __restrict__ x,
                                                   const short* __restrict__ wfrag,
                                                   unsigned short* __restrict__ hb) {
    const int wave = threadIdx.x >> 6;
    const int lane = threadIdx.x & 63;
    const int rowbase = (blockIdx.x * 4 + wave) * 16;
    const int arow = rowbase + (lane & 15);
    const int kgrp = lane >> 4;

    f32x4 acc[4];
#pragma unroll
    for (int c = 0; c < 4; ++c) acc[c] = (f32x4){0.f, 0.f, 0.f, 0.f};

    const float* ap = x + (size_t)arow * FIN + kgrp * 8;
#pragma unroll
    for (int kt = 0; kt < 9; ++kt) {
        f32x4 lo = *(const f32x4*)(ap + kt * 32);
        f32x4 hi = *(const f32x4*)(ap + kt * 32 + 4);
        short8 afr;
        afr[0] = (short)f2bfbits(lo[0]); afr[1] = (short)f2bfbits(lo[1]);
        afr[2] = (short)f2bfbits(lo[2]); afr[3] = (short)f2bfbits(lo[3]);
        afr[4] = (short)f2bfbits(hi[0]); afr[5] = (short)f2bfbits(hi[1]);
        afr[6] = (short)f2bfbits(hi[2]); afr[7] = (short)f2bfbits(hi[3]);
#pragma unroll
        for (int ct = 0; ct < 4; ++ct) {
            short8 bfr = *(const short8*)(wfrag + ((size_t)(ct * 10 + kt) * 64 + lane) * 8);
            acc[ct] = __builtin_amdgcn_mfma_f32_16x16x32_bf16(afr, bfr, acc[ct], 0, 0, 0);
        }
    }
    {   // K tail: k 288..319, valid only k<300
        short8 afr;
#pragma unroll
        for (int e = 0; e < 8; ++e) {
            int k = 288 + kgrp * 8 + e;
            float v = (k < FIN) ? x[(size_t)arow * FIN + k] : 0.f;
            afr[e] = (short)f2bfbits(v);
        }
#pragma unroll
        for (int ct = 0; ct < 4; ++ct) {
            short8 bfr = *(const short8*)(wfrag + ((size_t)(ct * 10 + 9) * 64 + lane) * 8);
            acc[ct] = __builtin_amdgcn_mfma_f32_16x16x32_bf16(afr, bfr, acc[ct], 0, 0, 0);
        }
    }
    // D layout: row = (lane>>4)*4 + r, col = ct*16 + (lane&15)
    const int orow = rowbase + (lane >> 4) * 4;
    const int colb = lane & 15;
#pragma unroll
    for (int ct = 0; ct < 4; ++ct)
#pragma unroll
        for (int r = 0; r < 4; ++r)
            hb[(size_t)(orow + r) * FOUT + ct * 16 + colb] = f2bfbits(acc[ct][r]);
}

// ---------------------------------------------------------------------------
// Per-subgraph aggregate + norm + PReLU + pool + anchor. NO float atomics:
// edges bucketed by dst into LDS (int atomics for ranks), register accum,
// wave-owned dst rows, f32 rsqrt(deg_out) scaling via rout[].
// ---------------------------------------------------------------------------
__global__ __launch_bounds__(256) void agg_pool_kernel(const unsigned short* __restrict__ hb,
                                                       const unsigned short* __restrict__ bkt,
                                                       const int* __restrict__ gcnt,
                                                       const float* __restrict__ bias,
                                                       const float* __restrict__ prelu,
                                                       float* __restrict__ out) {
    __shared__ unsigned short hl[SSUB][FOUT];       // 16 KB bf16 bits
    __shared__ unsigned char  es[SSUB][64];         // 8 KB per-dst src lists
    __shared__ int   din[SSUB];
    __shared__ int   dout[SSUB];
    __shared__ float rout[SSUB];
    __shared__ float ps[4][FOUT];

    const int g = blockIdx.x;
    const int t = threadIdx.x;
    const int lane = t & 63;
    const int w = t >> 6;

    // load h tile (straight bf16 copy, 4 x ushort8 per thread)
    {
        const ushort8* hsrc = (const ushort8*)(hb + (size_t)g * SSUB * FOUT);
        ushort8* hdst = (ushort8*)&hl[0][0];
        for (int i = t; i < 1024; i += 256) hdst[i] = hsrc[i];
    }
    if (t < SSUB) { din[t] = 0; dout[t] = 0; }
    __syncthreads();

    const int cnt = gcnt[g];
    const unsigned short* eb = bkt + ((size_t)g << 12);

    // bucket edges by dst into LDS (int atomics only)
    for (int i = t; i < cnt; i += 256) {
        unsigned e = eb[i];
        int s = e >> 7, d = e & 127;
        int r = atomicAdd(&din[d], 1);
        es[d][r & 63] = (unsigned char)s;
        atomicAdd(&dout[s], 1);
    }
    __syncthreads();
    if (t < SSUB) rout[t] = rsqrtf((float)max(dout[t], 1));
    __syncthreads();

    // register aggregation: wave w owns dst rows w, w+4, ...
    const float bv = bias[lane];
    const float a = prelu[0];
    float pool = 0.f;
#pragma unroll 4
    for (int ii = 0; ii < 32; ++ii) {
        int d = w + 4 * ii;
        int cd = min(din[d], 64);
        float accv = 0.f;
        const unsigned* ew = (const unsigned*)&es[d][0];
        int nw = (cd + 3) >> 2;
        for (int p = 0; p < nw; ++p) {
            unsigned wd = ew[p];                        // broadcast LDS read
            int rem = cd - p * 4;
#pragma unroll
            for (int b = 0; b < 4; ++b) {
                if (b < rem) {                          // wave-uniform predicate
                    int s = (wd >> (8 * b)) & 127;
                    accv += bf2f(hl[s][lane]) * rout[s];
                }
            }
        }
        float v = accv * rsqrtf((float)max(din[d], 1)) + bv;
        v = (v > 0.f) ? v : a * v;
        if (d == SSUB - 1)
            out[(size_t)(BSUB + g) * FOUT + lane] = v;  // anchor (wave 3)
        else
            pool += v;
    }
    ps[w][lane] = pool;
    __syncthreads();
    if (w == 0) {
        float s = (ps[0][lane] + ps[1][lane]) + (ps[2][lane] + ps[3][lane]);
        out[(size_t)g * FOUT + lane] = s * (1.0f / 127.0f);
    }
}

// ---------------------------------------------------------------------------
extern "C" void kernel_launch(void* const* d_in, const int* in_sizes, int n_in,
                              void* d_out, int out_size, void* d_ws, size_t ws_size,
                              hipStream_t stream) {
    const float* in_feat = (const float*)d_in[0];
    const float* W       = (const float*)d_in[1];
    const float* bias    = (const float*)d_in[2];
    const float* prelu   = (const float*)d_in[3];
    const int*   src     = (const int*)d_in[4];
    const int*   dst     = (const int*)d_in[5];
    float* out = (float*)d_out;

    char* ws = (char*)d_ws;
    int*            gcnt  = (int*)(ws);                         // 4 KB
    short*          wfrag = (short*)(ws + 65536);               // 40 KB
    unsigned short* bkt   = (unsigned short*)(ws + (1u << 20)); // 8 MB (1024 x 4096 u16)
    unsigned short* hb    = (unsigned short*)(ws + (16u << 20)); // 16 MB bf16 h

    hipLaunchKernelGGL(prep_w_kernel,   dim3(10),        dim3(256), 0, stream, W, wfrag, gcnt);
    hipLaunchKernelGGL(bucket_kernel,   dim3(NCHUNK),    dim3(256), 0, stream, src, dst, gcnt, bkt);
    hipLaunchKernelGGL(gemm_kernel,     dim3(NNODES/64), dim3(256), 0, stream, in_feat, wfrag, hb);
    hipLaunchKernelGGL(agg_pool_kernel, dim3(BSUB),      dim3(256), 0, stream, hb, bkt, gcnt, bias, prelu, out);
}

// Round 6
// 120.902 us; speedup vs baseline: 1.0009x; 1.0009x over previous
//
#include <hip/hip_runtime.h>
#include <hip/hip_bf16.h>

#define NNODES 131072
#define NEDGES 2097152
#define BSUB   1024
#define SSUB   128
#define FIN    300
#define FOUT   64
#define NCHUNK 256
#define CHEDGE 8192

typedef __attribute__((ext_vector_type(8))) short short8;
typedef __attribute__((ext_vector_type(8))) unsigned short ushort8;
typedef __attribute__((ext_vector_type(4))) float f32x4;

// hardware RNE f32->bf16 (compiler lowers pairs to v_cvt_pk_bf16_f32)
__device__ inline unsigned short f2bfbits(float f) {
    union { __hip_bfloat16 h; unsigned short u; } cv;
    cv.h = __float2bfloat16(f);
    return cv.u;
}
__device__ inline float bf2f(unsigned short b) {
    return __uint_as_float(((unsigned)b) << 16);
}

// ---------------------------------------------------------------------------
// Pack W [300][64] f32 into MFMA B-fragment layout (K padded to 320) AND
// zero the 1024-entry gcnt array (avoids a graph memset node).
// ---------------------------------------------------------------------------
__global__ __launch_bounds__(256) void prep_w_kernel(const float* __restrict__ W,
                                                     short* __restrict__ wfrag,
                                                     int* __restrict__ gcnt) {
    int idx = blockIdx.x * 256 + threadIdx.x;     // grid 10 x 256 = 2560
    if (idx < BSUB) gcnt[idx] = 0;
    if (idx >= 2560) return;
    int ct   = idx / 640;
    int rem  = idx % 640;
    int kt   = rem / 64;
    int lane = rem % 64;
    int col  = ct * 16 + (lane & 15);
    int kb   = kt * 32 + (lane >> 4) * 8;
#pragma unroll
    for (int e = 0; e < 8; ++e) {
        int k = kb + e;
        float v = (k < FIN) ? W[(size_t)k * FOUT + col] : 0.f;
        wfrag[(size_t)idx * 8 + e] = (short)f2bfbits(v);
    }
}

// ---------------------------------------------------------------------------
// Heterogeneous kernel: blocks [0, NCHUNK) bucket edges; blocks [NCHUNK, ..)
// run the MFMA GEMM. The two tasks are data-independent — co-scheduling hides
// the atomic-bound bucket work under the BW-bound GEMM.
//
// Bucket: per-chunk LDS histogram (4 KB only), one global atomic per nonzero
// bin reserves a range, second pass re-reads src/dst (L2-hot) and scatters
// packed (src_loc<<7 | dst_loc) u16 into fixed 4096-entry buckets.
// GEMM: h = in_feat @ W (unnormalized), one wave per 16 rows, A-frags loaded
// from global f32 and hw-converted to bf16; writes bf16 h.
// ---------------------------------------------------------------------------
__global__ __launch_bounds__(256) void bucket_gemm_kernel(const int* __restrict__ src,
                                                          const int* __restrict__ dst,
                                                          int* __restrict__ gcnt,
                                                          unsigned short* __restrict__ bkt,
                                                          const float* __restrict__ x,
                                                          const short* __restrict__ wfrag,
                                                          unsigned short* __restrict__ hb) {
    if (blockIdx.x < NCHUNK) {
        // ---------------- bucket path ----------------
        __shared__ int hist[BSUB];                 // 4 KB (hist, then cursor)
        const int cb = blockIdx.x;
        const int t = threadIdx.x;
        for (int i = t; i < BSUB; i += 256) hist[i] = 0;
        __syncthreads();
        const int4* sp = (const int4*)(src + (size_t)cb * CHEDGE);
        for (int i = t; i < CHEDGE / 4; i += 256) {
            int4 v = sp[i];
            atomicAdd(&hist[v.x >> 7], 1);
            atomicAdd(&hist[v.y >> 7], 1);
            atomicAdd(&hist[v.z >> 7], 1);
            atomicAdd(&hist[v.w >> 7], 1);
        }
        __syncthreads();
        for (int i = t; i < BSUB; i += 256) {
            int c = hist[i];
            hist[i] = c ? atomicAdd(&gcnt[i], c) : 0;   // hist becomes cursor
        }
        __syncthreads();
        const int4* dp = (const int4*)(dst + (size_t)cb * CHEDGE);
        for (int i = t; i < CHEDGE / 4; i += 256) {
            int4 s4 = sp[i], d4 = dp[i];                // sp re-read is L1/L2-hot
#pragma unroll
            for (int k = 0; k < 4; ++k) {
                int s = (k == 0) ? s4.x : (k == 1) ? s4.y : (k == 2) ? s4.z : s4.w;
                int d = (k == 0) ? d4.x : (k == 1) ? d4.y : (k == 2) ? d4.z : d4.w;
                int g = s >> 7;
                int r = atomicAdd(&hist[g], 1);
                bkt[((size_t)g << 12) + r] = (unsigned short)(((s & 127) << 7) | (d & 127));
            }
        }
        return;
    }
    // ---------------- GEMM path ----------------
    const int wave = threadIdx.x >> 6;
    const int lane = threadIdx.x & 63;
    const int rowbase = ((blockIdx.x - NCHUNK) * 4 + wave) * 16;
    const int arow = rowbase + (lane & 15);
    const int kgrp = lane >> 4;

    f32x4 acc[4];
#pragma unroll
    for (int c = 0; c < 4; ++c) acc[c] = (f32x4){0.f, 0.f, 0.f, 0.f};

    const float* ap = x + (size_t)arow * FIN + kgrp * 8;
#pragma unroll
    for (int kt = 0; kt < 9; ++kt) {
        f32x4 lo = *(const f32x4*)(ap + kt * 32);
        f32x4 hi = *(const f32x4*)(ap + kt * 32 + 4);
        short8 afr;
        afr[0] = (short)f2bfbits(lo[0]); afr[1] = (short)f2bfbits(lo[1]);
        afr[2] = (short)f2bfbits(lo[2]); afr[3] = (short)f2bfbits(lo[3]);
        afr[4] = (short)f2bfbits(hi[0]); afr[5] = (short)f2bfbits(hi[1]);
        afr[6] = (short)f2bfbits(hi[2]); afr[7] = (short)f2bfbits(hi[3]);
#pragma unroll
        for (int ct = 0; ct < 4; ++ct) {
            short8 bfr = *(const short8*)(wfrag + ((size_t)(ct * 10 + kt) * 64 + lane) * 8);
            acc[ct] = __builtin_amdgcn_mfma_f32_16x16x32_bf16(afr, bfr, acc[ct], 0, 0, 0);
        }
    }
    {   // K tail: k 288..319, valid only k<300
        short8 afr;
#pragma unroll
        for (int e = 0; e < 8; ++e) {
            int k = 288 + kgrp * 8 + e;
            float v = (k < FIN) ? x[(size_t)arow * FIN + k] : 0.f;
            afr[e] = (short)f2bfbits(v);
        }
#pragma unroll
        for (int ct = 0; ct < 4; ++ct) {
            short8 bfr = *(const short8*)(wfrag + ((size_t)(ct * 10 + 9) * 64 + lane) * 8);
            acc[ct] = __builtin_amdgcn_mfma_f32_16x16x32_bf16(afr, bfr, acc[ct], 0, 0, 0);
        }
    }
    // D layout: row = (lane>>4)*4 + r, col = ct*16 + (lane&15)
    const int orow = rowbase + (lane >> 4) * 4;
    const int colb = lane & 15;
#pragma unroll
    for (int ct = 0; ct < 4; ++ct)
#pragma unroll
        for (int r = 0; r < 4; ++r)
            hb[(size_t)(orow + r) * FOUT + ct * 16 + colb] = f2bfbits(acc[ct][r]);
}

// ---------------------------------------------------------------------------
// Per-subgraph aggregate + norm + PReLU + pool + anchor. NO float atomics:
// edges bucketed by dst into LDS (int atomics for ranks), register accum,
// wave-owned dst rows, f32 rsqrt(deg_out) scaling via rout[].
// ---------------------------------------------------------------------------
__global__ __launch_bounds__(256) void agg_pool_kernel(const unsigned short* __restrict__ hb,
                                                       const unsigned short* __restrict__ bkt,
                                                       const int* __restrict__ gcnt,
                                                       const float* __restrict__ bias,
                                                       const float* __restrict__ prelu,
                                                       float* __restrict__ out) {
    __shared__ unsigned short hl[SSUB][FOUT];       // 16 KB bf16 bits
    __shared__ unsigned char  es[SSUB][64];         // 8 KB per-dst src lists
    __shared__ int   din[SSUB];
    __shared__ int   dout[SSUB];
    __shared__ float rout[SSUB];
    __shared__ float ps[4][FOUT];

    const int g = blockIdx.x;
    const int t = threadIdx.x;
    const int lane = t & 63;
    const int w = t >> 6;

    // load h tile (straight bf16 copy, 4 x ushort8 per thread)
    {
        const ushort8* hsrc = (const ushort8*)(hb + (size_t)g * SSUB * FOUT);
        ushort8* hdst = (ushort8*)&hl[0][0];
        for (int i = t; i < 1024; i += 256) hdst[i] = hsrc[i];
    }
    if (t < SSUB) { din[t] = 0; dout[t] = 0; }
    __syncthreads();

    const int cnt = gcnt[g];
    const unsigned short* eb = bkt + ((size_t)g << 12);

    // bucket edges by dst into LDS (int atomics only)
    for (int i = t; i < cnt; i += 256) {
        unsigned e = eb[i];
        int s = e >> 7, d = e & 127;
        int r = atomicAdd(&din[d], 1);
        es[d][r & 63] = (unsigned char)s;
        atomicAdd(&dout[s], 1);
    }
    __syncthreads();
    if (t < SSUB) rout[t] = rsqrtf((float)max(dout[t], 1));
    __syncthreads();

    // register aggregation: wave w owns dst rows w, w+4, ...
    const float bv = bias[lane];
    const float a = prelu[0];
    float pool = 0.f;
#pragma unroll 4
    for (int ii = 0; ii < 32; ++ii) {
        int d = w + 4 * ii;
        int cd = min(din[d], 64);
        float accv = 0.f;
        const unsigned* ew = (const unsigned*)&es[d][0];
        int nw = (cd + 3) >> 2;
        for (int p = 0; p < nw; ++p) {
            unsigned wd = ew[p];                        // broadcast LDS read
            int rem = cd - p * 4;
#pragma unroll
            for (int b = 0; b < 4; ++b) {
                if (b < rem) {                          // wave-uniform predicate
                    int s = (wd >> (8 * b)) & 127;
                    accv += bf2f(hl[s][lane]) * rout[s];
                }
            }
        }
        float v = accv * rsqrtf((float)max(din[d], 1)) + bv;
        v = (v > 0.f) ? v : a * v;
        if (d == SSUB - 1)
            out[(size_t)(BSUB + g) * FOUT + lane] = v;  // anchor (wave 3)
        else
            pool += v;
    }
    ps[w][lane] = pool;
    __syncthreads();
    if (w == 0) {
        float s = (ps[0][lane] + ps[1][lane]) + (ps[2][lane] + ps[3][lane]);
        out[(size_t)g * FOUT + lane] = s * (1.0f / 127.0f);
    }
}

// ---------------------------------------------------------------------------
extern "C" void kernel_launch(void* const* d_in, const int* in_sizes, int n_in,
                              void* d_out, int out_size, void* d_ws, size_t ws_size,
                              hipStream_t stream) {
    const float* in_feat = (const float*)d_in[0];
    const float* W       = (const float*)d_in[1];
    const float* bias    = (const float*)d_in[2];
    const float* prelu   = (const float*)d_in[3];
    const int*   src     = (const int*)d_in[4];
    const int*   dst     = (const int*)d_in[5];
    float* out = (float*)d_out;

    char* ws = (char*)d_ws;
    int*            gcnt  = (int*)(ws);                          // 4 KB
    short*          wfrag = (short*)(ws + 65536);                // 40 KB
    unsigned short* bkt   = (unsigned short*)(ws + (1u << 20));  // 8 MB (1024 x 4096 u16)
    unsigned short* hb    = (unsigned short*)(ws + (16u << 20)); // 16 MB bf16 h

    hipLaunchKernelGGL(prep_w_kernel,     dim3(10),                 dim3(256), 0, stream, W, wfrag, gcnt);
    hipLaunchKernelGGL(bucket_gemm_kernel,dim3(NCHUNK + NNODES/64), dim3(256), 0, stream,
                       src, dst, gcnt, bkt, in_feat, wfrag, hb);
    hipLaunchKernelGGL(agg_pool_kernel,   dim3(BSUB),               dim3(256), 0, stream, hb, bkt, gcnt, bias, prelu, out);
}

// Round 7
// 115.500 us; speedup vs baseline: 1.0478x; 1.0468x over previous
//
#include <hip/hip_runtime.h>
#include <hip/hip_bf16.h>

#define NNODES 131072
#define NEDGES 2097152
#define BSUB   1024
#define SSUB   128
#define FIN    300
#define FOUT   64
#define NCHUNK 256
#define CHEDGE 8192

typedef __attribute__((ext_vector_type(8))) short short8;
typedef __attribute__((ext_vector_type(8))) unsigned short ushort8;
typedef __attribute__((ext_vector_type(4))) float f32x4;

// hardware RNE f32->bf16 (compiler lowers pairs to v_cvt_pk_bf16_f32)
__device__ inline unsigned short f2bfbits(float f) {
    union { __hip_bfloat16 h; unsigned short u; } cv;
    cv.h = __float2bfloat16(f);
    return cv.u;
}
__device__ inline float bf2f(unsigned short b) {
    return __uint_as_float(((unsigned)b) << 16);
}

// ---------------------------------------------------------------------------
// Pack W [300][64] f32 into MFMA B-fragment layout (K padded to 320) AND
// zero the 1024-entry gcnt array (avoids a graph memset node).
// ---------------------------------------------------------------------------
__global__ __launch_bounds__(256) void prep_w_kernel(const float* __restrict__ W,
                                                     short* __restrict__ wfrag,
                                                     int* __restrict__ gcnt) {
    int idx = blockIdx.x * 256 + threadIdx.x;     // grid 10 x 256 = 2560
    if (idx < BSUB) gcnt[idx] = 0;
    if (idx >= 2560) return;
    int ct   = idx / 640;
    int rem  = idx % 640;
    int kt   = rem / 64;
    int lane = rem % 64;
    int col  = ct * 16 + (lane & 15);
    int kb   = kt * 32 + (lane >> 4) * 8;
#pragma unroll
    for (int e = 0; e < 8; ++e) {
        int k = kb + e;
        float v = (k < FIN) ? W[(size_t)k * FOUT + col] : 0.f;
        wfrag[(size_t)idx * 8 + e] = (short)f2bfbits(v);
    }
}

// ---------------------------------------------------------------------------
// Heterogeneous kernel: blocks [0, NCHUNK) bucket edges; blocks [NCHUNK, ..)
// run the MFMA GEMM (data-independent tasks, co-scheduled).
//
// GEMM path (the fix this round): ALL 20 A-strip f32x4 loads are issued
// back-to-back into registers BEFORE any cvt/MFMA — ~20 outstanding loads
// per lane instead of the ~2-3 the compiler kept at VGPR=56 (R6 was pure
// latency-bound: VALUBusy 2.8%, HBM 15%). Tail loads are vector + kgrp-
// predicated only for OOB safety (wfrag k>=300 rows are zero, so A values
// there are don't-cares). Epilogue transposes through wave-private LDS to
// emit 2 coalesced ushort8 stores instead of 16 scattered 2B stores.
// ---------------------------------------------------------------------------
__global__ __launch_bounds__(256) void bucket_gemm_kernel(const int* __restrict__ src,
                                                          const int* __restrict__ dst,
                                                          int* __restrict__ gcnt,
                                                          unsigned short* __restrict__ bkt,
                                                          const float* __restrict__ x,
                                                          const short* __restrict__ wfrag,
                                                          unsigned short* __restrict__ hb) {
    __shared__ int hist[BSUB];                      // bucket path (4 KB)
    __shared__ unsigned short st[4][16][FOUT];      // gemm epilogue (8 KB)

    if (blockIdx.x < NCHUNK) {
        // ---------------- bucket path ----------------
        const int cb = blockIdx.x;
        const int t = threadIdx.x;
        for (int i = t; i < BSUB; i += 256) hist[i] = 0;
        __syncthreads();
        const int4* sp = (const int4*)(src + (size_t)cb * CHEDGE);
        for (int i = t; i < CHEDGE / 4; i += 256) {
            int4 v = sp[i];
            atomicAdd(&hist[v.x >> 7], 1);
            atomicAdd(&hist[v.y >> 7], 1);
            atomicAdd(&hist[v.z >> 7], 1);
            atomicAdd(&hist[v.w >> 7], 1);
        }
        __syncthreads();
        for (int i = t; i < BSUB; i += 256) {
            int c = hist[i];
            hist[i] = c ? atomicAdd(&gcnt[i], c) : 0;   // hist becomes cursor
        }
        __syncthreads();
        const int4* dp = (const int4*)(dst + (size_t)cb * CHEDGE);
        for (int i = t; i < CHEDGE / 4; i += 256) {
            int4 s4 = sp[i], d4 = dp[i];                // sp re-read is L1/L2-hot
#pragma unroll
            for (int k = 0; k < 4; ++k) {
                int s = (k == 0) ? s4.x : (k == 1) ? s4.y : (k == 2) ? s4.z : s4.w;
                int d = (k == 0) ? d4.x : (k == 1) ? d4.y : (k == 2) ? d4.z : d4.w;
                int g = s >> 7;
                int r = atomicAdd(&hist[g], 1);
                bkt[((size_t)g << 12) + r] = (unsigned short)(((s & 127) << 7) | (d & 127));
            }
        }
        return;
    }
    // ---------------- GEMM path ----------------
    const int wave = threadIdx.x >> 6;
    const int lane = threadIdx.x & 63;
    const int rowbase = ((blockIdx.x - NCHUNK) * 4 + wave) * 16;
    const int arow = rowbase + (lane & 15);
    const int kgrp = lane >> 4;
    const float* ap = x + (size_t)arow * FIN + kgrp * 8;

    // --- issue ALL A loads up front (20 outstanding f32x4 per lane) ---
    f32x4 lo[10], hi[10];
#pragma unroll
    for (int kt = 0; kt < 9; ++kt) {
        lo[kt] = *(const f32x4*)(ap + kt * 32);
        hi[kt] = *(const f32x4*)(ap + kt * 32 + 4);
    }
    lo[9] = (f32x4){0.f, 0.f, 0.f, 0.f};
    hi[9] = (f32x4){0.f, 0.f, 0.f, 0.f};
    if (kgrp == 0) {               // k 288..295 (all < 300)
        lo[9] = *(const f32x4*)(ap + 288);
        hi[9] = *(const f32x4*)(ap + 288 + 4);
    } else if (kgrp == 1) {        // k 296..299 valid; 300..303 are don't-care
        lo[9] = *(const f32x4*)(ap + 288);
    }

    f32x4 acc[4];
#pragma unroll
    for (int c = 0; c < 4; ++c) acc[c] = (f32x4){0.f, 0.f, 0.f, 0.f};

#pragma unroll
    for (int kt = 0; kt < 10; ++kt) {
        short8 afr;
        afr[0] = (short)f2bfbits(lo[kt][0]); afr[1] = (short)f2bfbits(lo[kt][1]);
        afr[2] = (short)f2bfbits(lo[kt][2]); afr[3] = (short)f2bfbits(lo[kt][3]);
        afr[4] = (short)f2bfbits(hi[kt][0]); afr[5] = (short)f2bfbits(hi[kt][1]);
        afr[6] = (short)f2bfbits(hi[kt][2]); afr[7] = (short)f2bfbits(hi[kt][3]);
#pragma unroll
        for (int ct = 0; ct < 4; ++ct) {
            short8 bfr = *(const short8*)(wfrag + ((size_t)(ct * 10 + kt) * 64 + lane) * 8);
            acc[ct] = __builtin_amdgcn_mfma_f32_16x16x32_bf16(afr, bfr, acc[ct], 0, 0, 0);
        }
    }

    // --- epilogue: wave-private LDS transpose -> 2 coalesced 16B stores ---
    // D layout: row = (lane>>4)*4 + r, col = ct*16 + (lane&15)
    {
        const int lrow = (lane >> 4) * 4;
        const int colb = lane & 15;
#pragma unroll
        for (int ct = 0; ct < 4; ++ct)
#pragma unroll
            for (int r = 0; r < 4; ++r)
                st[wave][lrow + r][ct * 16 + colb] = f2bfbits(acc[ct][r]);
        // LDS is wave-synchronous: reads below see this wave's writes.
        const ushort8* sv = (const ushort8*)&st[wave][0][0];   // 128 x 16B
        ushort8* hout = (ushort8*)(hb + (size_t)rowbase * FOUT);
#pragma unroll
        for (int i = 0; i < 2; ++i)
            hout[lane + i * 64] = sv[lane + i * 64];
    }
}

// ---------------------------------------------------------------------------
// Per-subgraph aggregate + norm + PReLU + pool + anchor. NO float atomics:
// edges bucketed by dst into LDS (int atomics for ranks), register accum,
// wave-owned dst rows, f32 rsqrt(deg_out) scaling via rout[].
// ---------------------------------------------------------------------------
__global__ __launch_bounds__(256) void agg_pool_kernel(const unsigned short* __restrict__ hb,
                                                       const unsigned short* __restrict__ bkt,
                                                       const int* __restrict__ gcnt,
                                                       const float* __restrict__ bias,
                                                       const float* __restrict__ prelu,
                                                       float* __restrict__ out) {
    __shared__ unsigned short hl[SSUB][FOUT];       // 16 KB bf16 bits
    __shared__ unsigned char  es[SSUB][64];         // 8 KB per-dst src lists
    __shared__ int   din[SSUB];
    __shared__ int   dout[SSUB];
    __shared__ float rout[SSUB];
    __shared__ float ps[4][FOUT];

    const int g = blockIdx.x;
    const int t = threadIdx.x;
    const int lane = t & 63;
    const int w = t >> 6;

    // load h tile (straight bf16 copy, 4 x ushort8 per thread)
    {
        const ushort8* hsrc = (const ushort8*)(hb + (size_t)g * SSUB * FOUT);
        ushort8* hdst = (ushort8*)&hl[0][0];
        for (int i = t; i < 1024; i += 256) hdst[i] = hsrc[i];
    }
    if (t < SSUB) { din[t] = 0; dout[t] = 0; }
    __syncthreads();

    const int cnt = gcnt[g];
    const unsigned short* eb = bkt + ((size_t)g << 12);

    // bucket edges by dst into LDS (int atomics only)
    for (int i = t; i < cnt; i += 256) {
        unsigned e = eb[i];
        int s = e >> 7, d = e & 127;
        int r = atomicAdd(&din[d], 1);
        es[d][r & 63] = (unsigned char)s;
        atomicAdd(&dout[s], 1);
    }
    __syncthreads();
    if (t < SSUB) rout[t] = rsqrtf((float)max(dout[t], 1));
    __syncthreads();

    // register aggregation: wave w owns dst rows w, w+4, ...
    const float bv = bias[lane];
    const float a = prelu[0];
    float pool = 0.f;
#pragma unroll 4
    for (int ii = 0; ii < 32; ++ii) {
        int d = w + 4 * ii;
        int cd = min(din[d], 64);
        float accv = 0.f;
        const unsigned* ew = (const unsigned*)&es[d][0];
        int nw = (cd + 3) >> 2;
        for (int p = 0; p < nw; ++p) {
            unsigned wd = ew[p];                        // broadcast LDS read
            int rem = cd - p * 4;
#pragma unroll
            for (int b = 0; b < 4; ++b) {
                if (b < rem) {                          // wave-uniform predicate
                    int s = (wd >> (8 * b)) & 127;
                    accv += bf2f(hl[s][lane]) * rout[s];
                }
            }
        }
        float v = accv * rsqrtf((float)max(din[d], 1)) + bv;
        v = (v > 0.f) ? v : a * v;
        if (d == SSUB - 1)
            out[(size_t)(BSUB + g) * FOUT + lane] = v;  // anchor (wave 3)
        else
            pool += v;
    }
    ps[w][lane] = pool;
    __syncthreads();
    if (w == 0) {
        float s = (ps[0][lane] + ps[1][lane]) + (ps[2][lane] + ps[3][lane]);
        out[(size_t)g * FOUT + lane] = s * (1.0f / 127.0f);
    }
}

// ---------------------------------------------------------------------------
extern "C" void kernel_launch(void* const* d_in, const int* in_sizes, int n_in,
                              void* d_out, int out_size, void* d_ws, size_t ws_size,
                              hipStream_t stream) {
    const float* in_feat = (const float*)d_in[0];
    const float* W       = (const float*)d_in[1];
    const float* bias    = (const float*)d_in[2];
    const float* prelu   = (const float*)d_in[3];
    const int*   src     = (const int*)d_in[4];
    const int*   dst     = (const int*)d_in[5];
    float* out = (float*)d_out;

    char* ws = (char*)d_ws;
    int*            gcnt  = (int*)(ws);                          // 4 KB
    short*          wfrag = (short*)(ws + 65536);                // 40 KB
    unsigned short* bkt   = (unsigned short*)(ws + (1u << 20));  // 8 MB (1024 x 4096 u16)
    unsigned short* hb    = (unsigned short*)(ws + (16u << 20)); // 16 MB bf16 h

    hipLaunchKernelGGL(prep_w_kernel,     dim3(10),                 dim3(256), 0, stream, W, wfrag, gcnt);
    hipLaunchKernelGGL(bucket_gemm_kernel,dim3(NCHUNK + NNODES/64), dim3(256), 0, stream,
                       src, dst, gcnt, bkt, in_feat, wfrag, hb);
    hipLaunchKernelGGL(agg_pool_kernel,   dim3(BSUB),               dim3(256), 0, stream, hb, bkt, gcnt, bias, prelu, out);
}

// Round 9
// 111.150 us; speedup vs baseline: 1.0888x; 1.0391x over previous
//
#include <hip/hip_runtime.h>
#include <hip/hip_bf16.h>

#define NNODES 131072
#define NEDGES 2097152
#define BSUB   1024
#define SSUB   128
#define FIN    300
#define FOUT   64
#define NCHUNK 256
#define CHEDGE 8192

typedef __attribute__((ext_vector_type(8))) short short8;
typedef __attribute__((ext_vector_type(8))) unsigned short ushort8;
typedef __attribute__((ext_vector_type(4))) float f32x4;

// hardware RNE f32->bf16 (compiler lowers pairs to v_cvt_pk_bf16_f32)
__device__ inline unsigned short f2bfbits(float f) {
    union { __hip_bfloat16 h; unsigned short u; } cv;
    cv.h = __float2bfloat16(f);
    return cv.u;
}
__device__ inline float bf2f(unsigned short b) {
    return __uint_as_float(((unsigned)b) << 16);
}

// async global->LDS DMA, 16B per lane; LDS dest = wave-uniform base + lane*16,
// global src is per-lane. Counted by vmcnt; __syncthreads() drains it.
__device__ inline void gload_lds16(const float* g, void* l) {
    __builtin_amdgcn_global_load_lds(
        (const __attribute__((address_space(1))) unsigned int*)g,
        (__attribute__((address_space(3))) unsigned int*)l,
        16, 0, 0);
}

// ---------------------------------------------------------------------------
// Pack W [300][64] f32 into MFMA B-fragment layout (K padded to 320) AND
// zero the 1024-entry gcnt array (avoids a graph memset node).
// ---------------------------------------------------------------------------
__global__ __launch_bounds__(256) void prep_w_kernel(const float* __restrict__ W,
                                                     short* __restrict__ wfrag,
                                                     int* __restrict__ gcnt) {
    int idx = blockIdx.x * 256 + threadIdx.x;     // grid 10 x 256 = 2560
    if (idx < BSUB) gcnt[idx] = 0;
    if (idx >= 2560) return;
    int ct   = idx / 640;
    int rem  = idx % 640;
    int kt   = rem / 64;
    int lane = rem % 64;
    int col  = ct * 16 + (lane & 15);
    int kb   = kt * 32 + (lane >> 4) * 8;
#pragma unroll
    for (int e = 0; e < 8; ++e) {
        int k = kb + e;
        float v = (k < FIN) ? W[(size_t)k * FOUT + col] : 0.f;
        wfrag[(size_t)idx * 8 + e] = (short)f2bfbits(v);
    }
}

// ---------------------------------------------------------------------------
// Heterogeneous kernel: blocks [0, NCHUNK) bucket edges; blocks [NCHUNK, ..)
// run the MFMA GEMM.
//
// GEMM: race-free async-staged structure (m97 shape):
//   issue 4 tail reg-loads (k 256..300, 16 VGPR)  -- lands during staging
//   issue ALL 64 DMA insts: bufA k[0,128), bufB k[128,256), src pre-swizzled
//   ONE __syncthreads()  (drains all DMA; only cross-wave handoff point)
//   kt0..7 from LDS (swizzled, conflict-free), kt8..9 from regs
//   epilogue transpose in the wave's OWN bufB slice (no cross-wave touch)
// ---------------------------------------------------------------------------
__global__ __launch_bounds__(256) void bucket_gemm_kernel(const int* __restrict__ src,
                                                          const int* __restrict__ dst,
                                                          int* __restrict__ gcnt,
                                                          unsigned short* __restrict__ bkt,
                                                          const float* __restrict__ x,
                                                          const short* __restrict__ wfrag,
                                                          unsigned short* __restrict__ hb) {
    __shared__ __align__(16) char smem[65536];

    if (blockIdx.x < NCHUNK) {
        // ---------------- bucket path ----------------
        int* hist = (int*)smem;                    // 4 KB (hist, then cursor)
        const int cb = blockIdx.x;
        const int t = threadIdx.x;
        for (int i = t; i < BSUB; i += 256) hist[i] = 0;
        __syncthreads();
        const int4* sp = (const int4*)(src + (size_t)cb * CHEDGE);
        for (int i = t; i < CHEDGE / 4; i += 256) {
            int4 v = sp[i];
            atomicAdd(&hist[v.x >> 7], 1);
            atomicAdd(&hist[v.y >> 7], 1);
            atomicAdd(&hist[v.z >> 7], 1);
            atomicAdd(&hist[v.w >> 7], 1);
        }
        __syncthreads();
        for (int i = t; i < BSUB; i += 256) {
            int c = hist[i];
            hist[i] = c ? atomicAdd(&gcnt[i], c) : 0;   // hist becomes cursor
        }
        __syncthreads();
        const int4* dp = (const int4*)(dst + (size_t)cb * CHEDGE);
        for (int i = t; i < CHEDGE / 4; i += 256) {
            int4 s4 = sp[i], d4 = dp[i];                // sp re-read is L1/L2-hot
#pragma unroll
            for (int k = 0; k < 4; ++k) {
                int s = (k == 0) ? s4.x : (k == 1) ? s4.y : (k == 2) ? s4.z : s4.w;
                int d = (k == 0) ? d4.x : (k == 1) ? d4.y : (k == 2) ? d4.z : d4.w;
                int g = s >> 7;
                int r = atomicAdd(&hist[g], 1);
                bkt[((size_t)g << 12) + r] = (unsigned short)(((s & 127) << 7) | (d & 127));
            }
        }
        return;
    }
    // ---------------- GEMM path ----------------
    char* bufA = smem;                  // 32 KB: k[0,128),   rows of 512 B
    char* bufB = smem + 32768;          // 32 KB: k[128,256), rows of 512 B

    const int wave = threadIdx.x >> 6;
    const int lane = threadIdx.x & 63;
    const int rowbase = (blockIdx.x - NCHUNK) * 64;
    const int rl = wave * 16 + (lane & 15);     // row within 64-row tile
    const int kg = lane >> 4;
    const int arow = rowbase + rl;

    // --- tail k[256,300): 4 reg loads per lane, issued FIRST, used LAST ---
    const float* arp = x + (size_t)arow * FIN;
    f32x4 t8a = *(const f32x4*)(arp + 256 + kg * 8);       // k 256+kg*8 ..+3
    f32x4 t8b = *(const f32x4*)(arp + 256 + kg * 8 + 4);   // k .. +7  (max 287)
    f32x4 t9a = (f32x4){0.f, 0.f, 0.f, 0.f};
    f32x4 t9b = (f32x4){0.f, 0.f, 0.f, 0.f};
    if (kg == 0) {
        t9a = *(const f32x4*)(arp + 288);                  // k 288..291
        t9b = *(const f32x4*)(arp + 292);                  // k 292..295
    } else if (kg == 1) {
        t9a = *(const f32x4*)(arp + 296);                  // k 296..299
    }                                                      // k>=300: zeros (B rows are 0)

    // --- issue ALL staging DMA back-to-back (16 insts/wave, no VGPR) ---
#pragma unroll
    for (int i = wave; i < 32; i += 4) {
        int o = i * 1024 + lane * 16;
        int row = o >> 9;                       // o / 512
        int c = o & 511;
        int csrc = c ^ ((row & 7) << 4);        // inverse of read-side swizzle
        gload_lds16(x + (size_t)(rowbase + row) * FIN + (csrc >> 2), bufA + i * 1024);
    }
#pragma unroll
    for (int i = wave; i < 32; i += 4) {
        int o = i * 1024 + lane * 16;
        int row = o >> 9;
        int c = o & 511;
        int csrc = c ^ ((row & 7) << 4);
        gload_lds16(x + (size_t)(rowbase + row) * FIN + 128 + (csrc >> 2), bufB + i * 1024);
    }

    f32x4 acc[4];
#pragma unroll
    for (int c = 0; c < 4; ++c) acc[c] = (f32x4){0.f, 0.f, 0.f, 0.f};

    const int sw = (rl & 7) << 4;

    __syncthreads();    // the ONLY barrier: drains all DMA, publishes bufA/bufB

    // --- kt 0..7 from LDS (each wave reads only its own 16-row slice) ---
#pragma unroll
    for (int kt = 0; kt < 8; ++kt) {
        const char* buf = (kt < 4) ? bufA : bufB;
        int c0 = (kt & 3) * 128 + kg * 32;
        f32x4 lo = *(const f32x4*)(buf + rl * 512 + (c0 ^ sw));
        f32x4 hi = *(const f32x4*)(buf + rl * 512 + ((c0 + 16) ^ sw));
        short8 afr;
        afr[0] = (short)f2bfbits(lo[0]); afr[1] = (short)f2bfbits(lo[1]);
        afr[2] = (short)f2bfbits(lo[2]); afr[3] = (short)f2bfbits(lo[3]);
        afr[4] = (short)f2bfbits(hi[0]); afr[5] = (short)f2bfbits(hi[1]);
        afr[6] = (short)f2bfbits(hi[2]); afr[7] = (short)f2bfbits(hi[3]);
#pragma unroll
        for (int ct = 0; ct < 4; ++ct) {
            short8 bfr = *(const short8*)(wfrag + ((size_t)(ct * 10 + kt) * 64 + lane) * 8);
            acc[ct] = __builtin_amdgcn_mfma_f32_16x16x32_bf16(afr, bfr, acc[ct], 0, 0, 0);
        }
    }
    // --- kt 8..9 from registers ---
#pragma unroll
    for (int kt = 8; kt < 10; ++kt) {
        f32x4 lo = (kt == 8) ? t8a : t9a;
        f32x4 hi = (kt == 8) ? t8b : t9b;
        short8 afr;
        afr[0] = (short)f2bfbits(lo[0]); afr[1] = (short)f2bfbits(lo[1]);
        afr[2] = (short)f2bfbits(lo[2]); afr[3] = (short)f2bfbits(lo[3]);
        afr[4] = (short)f2bfbits(hi[0]); afr[5] = (short)f2bfbits(hi[1]);
        afr[6] = (short)f2bfbits(hi[2]); afr[7] = (short)f2bfbits(hi[3]);
#pragma unroll
        for (int ct = 0; ct < 4; ++ct) {
            short8 bfr = *(const short8*)(wfrag + ((size_t)(ct * 10 + kt) * 64 + lane) * 8);
            acc[ct] = __builtin_amdgcn_mfma_f32_16x16x32_bf16(afr, bfr, acc[ct], 0, 0, 0);
        }
    }

    // --- epilogue: transpose in the wave's OWN bufB slice -> coalesced stores
    // Wave w's compute reads bufB bytes [w*8192, w*8192+8192) only; writing the
    // first 2 KB of that same slice after its own reads is wave-private.
    {
        unsigned short* st = (unsigned short*)(bufB + wave * 8192);   // [16][64]
        const int lrow = (lane >> 4) * 4;
        const int colb = lane & 15;
#pragma unroll
        for (int ct = 0; ct < 4; ++ct)
#pragma unroll
            for (int r = 0; r < 4; ++r)
                st[(lrow + r) * FOUT + ct * 16 + colb] = f2bfbits(acc[ct][r]);
        const ushort8* sv = (const ushort8*)st;                       // 128 x 16B
        ushort8* hout = (ushort8*)(hb + (size_t)(rowbase + wave * 16) * FOUT);
        hout[lane] = sv[lane];
        hout[lane + 64] = sv[lane + 64];
    }
}

// ---------------------------------------------------------------------------
// Per-subgraph aggregate + norm + PReLU + pool + anchor. NO float atomics:
// edges bucketed by dst into LDS (int atomics for ranks), register accum,
// wave-owned dst rows, f32 rsqrt(deg_out) scaling via rout[].
// ---------------------------------------------------------------------------
__global__ __launch_bounds__(256) void agg_pool_kernel(const unsigned short* __restrict__ hb,
                                                       const unsigned short* __restrict__ bkt,
                                                       const int* __restrict__ gcnt,
                                                       const float* __restrict__ bias,
                                                       const float* __restrict__ prelu,
                                                       float* __restrict__ out) {
    __shared__ unsigned short hl[SSUB][FOUT];       // 16 KB bf16 bits
    __shared__ unsigned char  es[SSUB][64];         // 8 KB per-dst src lists
    __shared__ int   din[SSUB];
    __shared__ int   dout[SSUB];
    __shared__ float rout[SSUB];
    __shared__ float ps[4][FOUT];

    const int g = blockIdx.x;
    const int t = threadIdx.x;
    const int lane = t & 63;
    const int w = t >> 6;

    // load h tile (straight bf16 copy, 4 x ushort8 per thread)
    {
        const ushort8* hsrc = (const ushort8*)(hb + (size_t)g * SSUB * FOUT);
        ushort8* hdst = (ushort8*)&hl[0][0];
        for (int i = t; i < 1024; i += 256) hdst[i] = hsrc[i];
    }
    if (t < SSUB) { din[t] = 0; dout[t] = 0; }
    __syncthreads();

    const int cnt = gcnt[g];
    const unsigned short* eb = bkt + ((size_t)g << 12);

    // bucket edges by dst into LDS (int atomics only)
    for (int i = t; i < cnt; i += 256) {
        unsigned e = eb[i];
        int s = e >> 7, d = e & 127;
        int r = atomicAdd(&din[d], 1);
        es[d][r & 63] = (unsigned char)s;
        atomicAdd(&dout[s], 1);
    }
    __syncthreads();
    if (t < SSUB) rout[t] = rsqrtf((float)max(dout[t], 1));
    __syncthreads();

    // register aggregation: wave w owns dst rows w, w+4, ...
    const float bv = bias[lane];
    const float a = prelu[0];
    float pool = 0.f;
#pragma unroll 4
    for (int ii = 0; ii < 32; ++ii) {
        int d = w + 4 * ii;
        int cd = min(din[d], 64);
        float accv = 0.f;
        const unsigned* ew = (const unsigned*)&es[d][0];
        int nw = (cd + 3) >> 2;
        for (int p = 0; p < nw; ++p) {
            unsigned wd = ew[p];                        // broadcast LDS read
            int rem = cd - p * 4;
#pragma unroll
            for (int b = 0; b < 4; ++b) {
                if (b < rem) {                          // wave-uniform predicate
                    int s = (wd >> (8 * b)) & 127;
                    accv += bf2f(hl[s][lane]) * rout[s];
                }
            }
        }
        float v = accv * rsqrtf((float)max(din[d], 1)) + bv;
        v = (v > 0.f) ? v : a * v;
        if (d == SSUB - 1)
            out[(size_t)(BSUB + g) * FOUT + lane] = v;  // anchor (wave 3)
        else
            pool += v;
    }
    ps[w][lane] = pool;
    __syncthreads();
    if (w == 0) {
        float s = (ps[0][lane] + ps[1][lane]) + (ps[2][lane] + ps[3][lane]);
        out[(size_t)g * FOUT + lane] = s * (1.0f / 127.0f);
    }
}

// ---------------------------------------------------------------------------
extern "C" void kernel_launch(void* const* d_in, const int* in_sizes, int n_in,
                              void* d_out, int out_size, void* d_ws, size_t ws_size,
                              hipStream_t stream) {
    const float* in_feat = (const float*)d_in[0];
    const float* W       = (const float*)d_in[1];
    const float* bias    = (const float*)d_in[2];
    const float* prelu   = (const float*)d_in[3];
    const int*   src     = (const int*)d_in[4];
    const int*   dst     = (const int*)d_in[5];
    float* out = (float*)d_out;

    char* ws = (char*)d_ws;
    int*            gcnt  = (int*)(ws);                          // 4 KB
    short*          wfrag = (short*)(ws + 65536);                // 40 KB
    unsigned short* bkt   = (unsigned short*)(ws + (1u << 20));  // 8 MB (1024 x 4096 u16)
    unsigned short* hb    = (unsigned short*)(ws + (16u << 20)); // 16 MB bf16 h

    hipLaunchKernelGGL(prep_w_kernel,     dim3(10),                 dim3(256), 0, stream, W, wfrag, gcnt);
    hipLaunchKernelGGL(bucket_gemm_kernel,dim3(NCHUNK + NNODES/64), dim3(256), 0, stream,
                       src, dst, gcnt, bkt, in_feat, wfrag, hb);
    hipLaunchKernelGGL(agg_pool_kernel,   dim3(BSUB),               dim3(256), 0, stream, hb, bkt, gcnt, bias, prelu, out);
}